// Round 1
// baseline (100.260 us; speedup 1.0000x reference)
//
#include <hip/hip_runtime.h>

typedef __attribute__((ext_vector_type(4))) float         f32x4;
typedef __attribute__((ext_vector_type(8))) short         s16x8;
typedef __attribute__((ext_vector_type(2))) unsigned int  u32x2;

#define M_   2048      // B*S
#define H_   128       // K
#define V_   20001     // N

#define BM   64
#define BN   64

__device__ __forceinline__ unsigned short f2bf(float f) {
    unsigned int u = __float_as_uint(f);
    u = (u + 0x7FFFu + ((u >> 16) & 1u)) >> 16;   // RNE
    return (unsigned short)u;
}

__global__ __launch_bounds__(256, 2)
void l2head_kernel(const float* __restrict__ x,
                   const float* __restrict__ emb,
                   const float* __restrict__ bias,
                   float* __restrict__ out)
{
    // LDS: row-major K-contiguous bf16 tiles, XOR-swizzled (byte ^= (row&7)<<4)
    __shared__ unsigned char a_raw[BM * 256];   // 64 rows x 128 bf16 (256B/row)
    __shared__ unsigned char b_raw[BN * 256];
    __shared__ float xsq[BM];
    __shared__ float esq[BN];
    __shared__ float bls[BN];

    const int tid  = threadIdx.x;
    const int lane = tid & 63;
    const int m0   = blockIdx.x * BM;   // 32 m-tiles (fastest -> share B tile)
    const int n0   = blockIdx.y * BN;   // 313 n-tiles

    // bias tile
    if (tid < BN) {
        int gn = n0 + tid;
        bls[tid] = (gn < V_) ? bias[gn] : 0.0f;
    }

    // ---- stage A: 64x128 f32 -> bf16 LDS, + row sum-of-squares ----
    {
        const f32x4* src = (const f32x4*)(x + (size_t)m0 * H_);
        #pragma unroll
        for (int i = 0; i < 8; ++i) {
            int f   = tid + i * 256;         // float4 index 0..2047
            int row = f >> 5;                // 32 float4 per row
            int c4  = f & 31;
            f32x4 v = src[f];
            unsigned int p0 = (unsigned int)f2bf(v[0]) | ((unsigned int)f2bf(v[1]) << 16);
            unsigned int p1 = (unsigned int)f2bf(v[2]) | ((unsigned int)f2bf(v[3]) << 16);
            int boff = (c4 * 8) ^ ((row & 7) << 4);
            u32x2 p = { p0, p1 };
            *(u32x2*)(&a_raw[row * 256 + boff]) = p;
            float ss = v[0]*v[0] + v[1]*v[1] + v[2]*v[2] + v[3]*v[3];
            // the 32 float4s of a row live in exactly one 32-lane group
            ss += __shfl_xor(ss, 1);  ss += __shfl_xor(ss, 2);
            ss += __shfl_xor(ss, 4);  ss += __shfl_xor(ss, 8);
            ss += __shfl_xor(ss, 16);
            if ((lane & 31) == 0) xsq[row] = ss;
        }
    }
    // ---- stage B: emb tile (N x K), guarded at V tail ----
    {
        #pragma unroll
        for (int i = 0; i < 8; ++i) {
            int f   = tid + i * 256;
            int row = f >> 5;
            int c4  = f & 31;
            int gn  = n0 + row;
            f32x4 v = { 0.f, 0.f, 0.f, 0.f };
            if (gn < V_) v = *(const f32x4*)(emb + (size_t)gn * H_ + c4 * 4);
            unsigned int p0 = (unsigned int)f2bf(v[0]) | ((unsigned int)f2bf(v[1]) << 16);
            unsigned int p1 = (unsigned int)f2bf(v[2]) | ((unsigned int)f2bf(v[3]) << 16);
            int boff = (c4 * 8) ^ ((row & 7) << 4);
            u32x2 p = { p0, p1 };
            *(u32x2*)(&b_raw[row * 256 + boff]) = p;
            float ss = v[0]*v[0] + v[1]*v[1] + v[2]*v[2] + v[3]*v[3];
            ss += __shfl_xor(ss, 1);  ss += __shfl_xor(ss, 2);
            ss += __shfl_xor(ss, 4);  ss += __shfl_xor(ss, 8);
            ss += __shfl_xor(ss, 16);
            if ((lane & 31) == 0) esq[row] = ss;
        }
    }
    __syncthreads();

    // ---- compute: 4 waves 2x2, each wave 32x32 = 2x2 fragments of 16x16 ----
    const int w  = tid >> 6;
    const int wm = w >> 1;
    const int wn = w & 1;
    const int lr = lane & 15;   // fragment row (A: m, B: n)
    const int lk = lane >> 4;   // k-group of 8

    f32x4 acc[2][2] = {};
    #pragma unroll
    for (int kk = 0; kk < 4; ++kk) {
        int kb = kk * 64 + lk * 16;
        s16x8 a[2], b[2];
        #pragma unroll
        for (int mi = 0; mi < 2; ++mi) {
            int row = wm * 32 + mi * 16 + lr;
            a[mi] = *(const s16x8*)(&a_raw[row * 256 + (kb ^ ((row & 7) << 4))]);
        }
        #pragma unroll
        for (int ni = 0; ni < 2; ++ni) {
            int row = wn * 32 + ni * 16 + lr;
            b[ni] = *(const s16x8*)(&b_raw[row * 256 + (kb ^ ((row & 7) << 4))]);
        }
        #pragma unroll
        for (int mi = 0; mi < 2; ++mi)
            #pragma unroll
            for (int ni = 0; ni < 2; ++ni)
                acc[mi][ni] = __builtin_amdgcn_mfma_f32_16x16x32_bf16(
                                  a[mi], b[ni], acc[mi][ni], 0, 0, 0);
    }

    // ---- epilogue: d2 = xsq + esq - 2*dot; out = bias - sqrt(max(d2,0)) ----
    // C/D layout: col = lane&15, row = (lane>>4)*4 + reg  [m89-verified]
    #pragma unroll
    for (int mi = 0; mi < 2; ++mi) {
        int mbase = wm * 32 + mi * 16 + lk * 4;
        #pragma unroll
        for (int ni = 0; ni < 2; ++ni) {
            int nloc = wn * 32 + ni * 16 + lr;
            int gn   = n0 + nloc;
            if (gn < V_) {
                float es = esq[nloc];
                float bb = bls[nloc];
                #pragma unroll
                for (int j = 0; j < 4; ++j) {
                    int   mloc = mbase + j;
                    float d2   = xsq[mloc] + es - 2.0f * acc[mi][ni][j];
                    d2 = fmaxf(d2, 0.0f);
                    out[(size_t)(m0 + mloc) * V_ + gn] = bb - __builtin_sqrtf(d2);
                }
            }
        }
    }
}

extern "C" void kernel_launch(void* const* d_in, const int* in_sizes, int n_in,
                              void* d_out, int out_size, void* d_ws, size_t ws_size,
                              hipStream_t stream) {
    const float* x    = (const float*)d_in[0];
    const float* emb  = (const float*)d_in[1];
    const float* bias = (const float*)d_in[2];
    float* out        = (float*)d_out;

    dim3 grid(M_ / BM, (V_ + BN - 1) / BN);   // (32, 313), m fastest
    l2head_kernel<<<grid, dim3(256), 0, stream>>>(x, emb, bias, out);
}

// Round 2
// 55.458 us; speedup vs baseline: 1.8079x; 1.8079x over previous
//
#include <hip/hip_runtime.h>

typedef __attribute__((ext_vector_type(4))) float         f32x4;
typedef __attribute__((ext_vector_type(4), aligned(4))) float f32x4u;  // V odd -> rows only 4B-aligned
typedef __attribute__((ext_vector_type(2))) float         f32x2;
typedef __attribute__((ext_vector_type(8))) short         s16x8;
typedef __attribute__((ext_vector_type(2))) unsigned int  u32x2;

#define M_     2048      // B*S
#define H_     128       // K
#define V_     20001     // N
#define VPAD_  20032     // padded to 64

#define BM   64
#define BN   64

// ws layout (bytes)
#define WS_XBF   0u
#define WS_EBF   524288u                     // 2048*256
#define WS_XSQ   5652480u                    // + 20032*256
#define WS_ESQ   5660672u                    // + 8192
#define WS_END   5740800u                    // + 20032*4

__device__ __forceinline__ unsigned short f2bf(float f) {
    unsigned int u = __float_as_uint(f);
    u = (u + 0x7FFFu + ((u >> 16) & 1u)) >> 16;   // RNE
    return (unsigned short)u;
}

// ---------------- prep: f32 -> bf16 rows + sum-of-squares, once ----------------
__global__ __launch_bounds__(256)
void prep_kernel(const float* __restrict__ x, const float* __restrict__ emb,
                 unsigned int* __restrict__ xbf, unsigned int* __restrict__ ebf,
                 float* __restrict__ xsq, float* __restrict__ esq)
{
    const int wid  = blockIdx.x * 4 + (threadIdx.x >> 6);   // one wave per row
    const int lane = threadIdx.x & 63;

    f32x2 v = { 0.f, 0.f };
    if (wid < M_) {
        v = *(const f32x2*)(x + (size_t)wid * H_ + lane * 2);
    } else {
        int er = wid - M_;
        if (er < V_) v = *(const f32x2*)(emb + (size_t)er * H_ + lane * 2);
    }
    unsigned int pk = (unsigned int)f2bf(v[0]) | ((unsigned int)f2bf(v[1]) << 16);
    float ss = v[0] * v[0] + v[1] * v[1];
    ss += __shfl_xor(ss, 1);  ss += __shfl_xor(ss, 2);  ss += __shfl_xor(ss, 4);
    ss += __shfl_xor(ss, 8);  ss += __shfl_xor(ss, 16); ss += __shfl_xor(ss, 32);

    if (wid < M_) {
        xbf[(size_t)wid * 64 + lane] = pk;
        if (lane == 0) xsq[wid] = ss;
    } else {
        int er = wid - M_;           // er < VPAD_; pad rows get zeros
        ebf[(size_t)er * 64 + lane] = pk;
        if (lane == 0) esq[er] = ss;
    }
}

// ---------------- main GEMM + epilogue ----------------
__global__ __launch_bounds__(256, 4)
void gemm_kernel(const unsigned int* __restrict__ xbf,
                 const unsigned int* __restrict__ ebf,
                 const float* __restrict__ xsq,
                 const float* __restrict__ esq,
                 const float* __restrict__ bias,
                 float* __restrict__ out)
{
    __shared__ unsigned char a_t[BM * 256];      // 64 rows x 256B bf16, XOR-swizzled
    __shared__ unsigned char b_t[BN * 256];
    __shared__ __align__(16) float xsq_s[BM];
    __shared__ __align__(16) float esq_s[BN];
    __shared__ __align__(16) float bias_s[BN];

    const int tid  = threadIdx.x;
    const int lane = tid & 63;
    const int m0   = blockIdx.x * BM;   // m fastest: 32 consecutive blocks share emb tile
    const int n0   = blockIdx.y * BN;

    // stage A,B: bf16 rows are 256B; swizzle via pre-swizzled SOURCE, linear LDS dest (m173)
    const char* asrc = (const char*)xbf + (size_t)m0 * 256;
    const char* bsrc = (const char*)ebf + (size_t)n0 * 256;   // n0+63 < VPAD, no guard
    #pragma unroll
    for (int i = 0; i < 4; ++i) {
        int c      = tid + i * 256;                       // 16B-chunk id
        int row    = c >> 4;
        int within = (c & 15) * 16;
        int so     = row * 256 + (within ^ ((row & 7) << 4));
        unsigned int ldsoff = (unsigned int)(((tid & ~63) + i * 256) * 16); // wave-uniform
        __builtin_amdgcn_global_load_lds(
            (const __attribute__((address_space(1))) unsigned int*)(asrc + so),
            (__attribute__((address_space(3))) unsigned int*)(a_t + ldsoff), 16, 0, 0);
        __builtin_amdgcn_global_load_lds(
            (const __attribute__((address_space(1))) unsigned int*)(bsrc + so),
            (__attribute__((address_space(3))) unsigned int*)(b_t + ldsoff), 16, 0, 0);
    }
    if (tid < 64)       xsq_s[tid]        = xsq[m0 + tid];
    else if (tid < 128) esq_s[tid - 64]   = esq[n0 + (tid - 64)];
    else if (tid < 192) { int gn = n0 + (tid - 128);
                          bias_s[tid - 128] = (gn < V_) ? bias[gn] : 0.0f; }
    __syncthreads();

    // compute: 4 waves 2x2; each wave 32x32 via 2x2 fragments x 4 K-steps
    const int w  = tid >> 6;
    const int wm = w >> 1;
    const int wn = w & 1;
    const int lr = lane & 15;
    const int lk = lane >> 4;

    f32x4 acc[2][2] = {};
    #pragma unroll
    for (int kk = 0; kk < 4; ++kk) {
        int kb = kk * 64 + lk * 16;
        s16x8 a[2], b[2];
        #pragma unroll
        for (int mi = 0; mi < 2; ++mi) {
            int row = wm * 32 + mi * 16 + lr;
            a[mi] = *(const s16x8*)(&a_t[row * 256 + (kb ^ ((row & 7) << 4))]);
        }
        #pragma unroll
        for (int ni = 0; ni < 2; ++ni) {
            int row = wn * 32 + ni * 16 + lr;
            b[ni] = *(const s16x8*)(&b_t[row * 256 + (kb ^ ((row & 7) << 4))]);
        }
        #pragma unroll
        for (int mi = 0; mi < 2; ++mi)
            #pragma unroll
            for (int ni = 0; ni < 2; ++ni)
                // swapped operands: D = D^T -> lane holds 4 consecutive n in regs
                acc[mi][ni] = __builtin_amdgcn_mfma_f32_16x16x32_bf16(
                                  b[ni], a[mi], acc[mi][ni], 0, 0, 0);
    }

    // epilogue: m = col(lane&15), n = row(lk*4 + j)  [swapped m89 mapping]
    #pragma unroll
    for (int mi = 0; mi < 2; ++mi) {
        int mloc = wm * 32 + mi * 16 + lr;
        float xs = xsq_s[mloc];
        size_t rowbase = (size_t)(m0 + mloc) * V_;
        #pragma unroll
        for (int ni = 0; ni < 2; ++ni) {
            int nloc = wn * 32 + ni * 16 + lk * 4;
            int gn   = n0 + nloc;
            f32x4 es = *(const f32x4*)(&esq_s[nloc]);
            f32x4 bb = *(const f32x4*)(&bias_s[nloc]);
            f32x4 r;
            #pragma unroll
            for (int j = 0; j < 4; ++j) {
                float d2 = xs + es[j] - 2.0f * acc[mi][ni][j];
                r[j] = bb[j] - __builtin_sqrtf(fmaxf(d2, 0.0f));
            }
            if (gn + 3 < V_) {
                *(f32x4u*)(out + rowbase + gn) = r;
            } else {
                #pragma unroll
                for (int j = 0; j < 4; ++j)
                    if (gn + j < V_) out[rowbase + gn + j] = r[j];
            }
        }
    }
}

// ---------------- fallback (round-1 single kernel) if ws too small ----------------
__global__ __launch_bounds__(256, 2)
void l2head_fallback(const float* __restrict__ x,
                     const float* __restrict__ emb,
                     const float* __restrict__ bias,
                     float* __restrict__ out)
{
    __shared__ unsigned char a_raw[BM * 256];
    __shared__ unsigned char b_raw[BN * 256];
    __shared__ float xsq[BM];
    __shared__ float esq[BN];
    __shared__ float bls[BN];

    const int tid  = threadIdx.x;
    const int lane = tid & 63;
    const int m0   = blockIdx.x * BM;
    const int n0   = blockIdx.y * BN;

    if (tid < BN) {
        int gn = n0 + tid;
        bls[tid] = (gn < V_) ? bias[gn] : 0.0f;
    }
    {
        const f32x4* src = (const f32x4*)(x + (size_t)m0 * H_);
        #pragma unroll
        for (int i = 0; i < 8; ++i) {
            int f = tid + i * 256, row = f >> 5, c4 = f & 31;
            f32x4 v = src[f];
            unsigned int p0 = (unsigned int)f2bf(v[0]) | ((unsigned int)f2bf(v[1]) << 16);
            unsigned int p1 = (unsigned int)f2bf(v[2]) | ((unsigned int)f2bf(v[3]) << 16);
            int boff = (c4 * 8) ^ ((row & 7) << 4);
            u32x2 p = { p0, p1 };
            *(u32x2*)(&a_raw[row * 256 + boff]) = p;
            float ss = v[0]*v[0] + v[1]*v[1] + v[2]*v[2] + v[3]*v[3];
            ss += __shfl_xor(ss, 1);  ss += __shfl_xor(ss, 2);
            ss += __shfl_xor(ss, 4);  ss += __shfl_xor(ss, 8);
            ss += __shfl_xor(ss, 16);
            if ((lane & 31) == 0) xsq[row] = ss;
        }
    }
    {
        #pragma unroll
        for (int i = 0; i < 8; ++i) {
            int f = tid + i * 256, row = f >> 5, c4 = f & 31;
            int gn = n0 + row;
            f32x4 v = { 0.f, 0.f, 0.f, 0.f };
            if (gn < V_) v = *(const f32x4*)(emb + (size_t)gn * H_ + c4 * 4);
            unsigned int p0 = (unsigned int)f2bf(v[0]) | ((unsigned int)f2bf(v[1]) << 16);
            unsigned int p1 = (unsigned int)f2bf(v[2]) | ((unsigned int)f2bf(v[3]) << 16);
            int boff = (c4 * 8) ^ ((row & 7) << 4);
            u32x2 p = { p0, p1 };
            *(u32x2*)(&b_raw[row * 256 + boff]) = p;
            float ss = v[0]*v[0] + v[1]*v[1] + v[2]*v[2] + v[3]*v[3];
            ss += __shfl_xor(ss, 1);  ss += __shfl_xor(ss, 2);
            ss += __shfl_xor(ss, 4);  ss += __shfl_xor(ss, 8);
            ss += __shfl_xor(ss, 16);
            if ((lane & 31) == 0) esq[row] = ss;
        }
    }
    __syncthreads();

    const int w  = tid >> 6;
    const int wm = w >> 1;
    const int wn = w & 1;
    const int lr = lane & 15;
    const int lk = lane >> 4;

    f32x4 acc[2][2] = {};
    #pragma unroll
    for (int kk = 0; kk < 4; ++kk) {
        int kb = kk * 64 + lk * 16;
        s16x8 a[2], b[2];
        #pragma unroll
        for (int mi = 0; mi < 2; ++mi) {
            int row = wm * 32 + mi * 16 + lr;
            a[mi] = *(const s16x8*)(&a_raw[row * 256 + (kb ^ ((row & 7) << 4))]);
        }
        #pragma unroll
        for (int ni = 0; ni < 2; ++ni) {
            int row = wn * 32 + ni * 16 + lr;
            b[ni] = *(const s16x8*)(&b_raw[row * 256 + (kb ^ ((row & 7) << 4))]);
        }
        #pragma unroll
        for (int mi = 0; mi < 2; ++mi)
            #pragma unroll
            for (int ni = 0; ni < 2; ++ni)
                acc[mi][ni] = __builtin_amdgcn_mfma_f32_16x16x32_bf16(
                                  a[mi], b[ni], acc[mi][ni], 0, 0, 0);
    }

    #pragma unroll
    for (int mi = 0; mi < 2; ++mi) {
        int mbase = wm * 32 + mi * 16 + lk * 4;
        #pragma unroll
        for (int ni = 0; ni < 2; ++ni) {
            int nloc = wn * 32 + ni * 16 + lr;
            int gn   = n0 + nloc;
            if (gn < V_) {
                float es = esq[nloc];
                float bb = bls[nloc];
                #pragma unroll
                for (int j = 0; j < 4; ++j) {
                    int   mloc = mbase + j;
                    float d2   = xsq[mloc] + es - 2.0f * acc[mi][ni][j];
                    d2 = fmaxf(d2, 0.0f);
                    out[(size_t)(m0 + mloc) * V_ + gn] = bb - __builtin_sqrtf(d2);
                }
            }
        }
    }
}

extern "C" void kernel_launch(void* const* d_in, const int* in_sizes, int n_in,
                              void* d_out, int out_size, void* d_ws, size_t ws_size,
                              hipStream_t stream) {
    const float* x    = (const float*)d_in[0];
    const float* emb  = (const float*)d_in[1];
    const float* bias = (const float*)d_in[2];
    float* out        = (float*)d_out;

    if (ws_size >= WS_END) {
        unsigned char* ws = (unsigned char*)d_ws;
        unsigned int* xbf = (unsigned int*)(ws + WS_XBF);
        unsigned int* ebf = (unsigned int*)(ws + WS_EBF);
        float* xsq        = (float*)(ws + WS_XSQ);
        float* esq        = (float*)(ws + WS_ESQ);

        int prep_blocks = (M_ + VPAD_) / 4;   // one wave per row, 4 waves/block
        prep_kernel<<<prep_blocks, 256, 0, stream>>>(x, emb, xbf, ebf, xsq, esq);

        dim3 grid(M_ / BM, (V_ + BN - 1) / BN);   // (32, 313)
        gemm_kernel<<<grid, dim3(256), 0, stream>>>(xbf, ebf, xsq, esq, bias, out);
    } else {
        dim3 grid(M_ / BM, (V_ + BN - 1) / BN);
        l2head_fallback<<<grid, dim3(256), 0, stream>>>(x, emb, bias, out);
    }
}